// Round 1
// baseline (244.565 us; speedup 1.0000x reference)
//
#include <hip/hip_runtime.h>

// Problem constants (from reference):
//   x: [B=32, T=2000, C=80] fp32, lengths: [32] fp32
//   out[b, t, c*CTX + i] = (t < round(T*lengths[b]) && 0 <= t+i-LEFT < T)
//                            ? x[b, t+i-LEFT, c] : 0
#define BB   32
#define TT   2000
#define CC   80
#define CTX  11
#define LEFTP 5

// 880 floats per (b,t) row -> 220 float4 per row
#define ROWQ ((CC * CTX) / 4)   // 220
#define TOTAL_Q (BB * TT * ROWQ) // 14,080,000 float4 elements

__global__ __launch_bounds__(256) void context_window_kernel(
    const float* __restrict__ x,
    const float* __restrict__ lengths,
    float* __restrict__ out)
{
    int gid = blockIdx.x * blockDim.x + threadIdx.x;
    if (gid >= TOTAL_Q) return;

    // decompose: gid = ((b * T) + t) * ROWQ + q
    int b   = gid / (TT * ROWQ);
    int rem = gid - b * (TT * ROWQ);
    int t   = rem / ROWQ;
    int q   = rem - t * ROWQ;
    int k0  = q * 4;  // first output-channel index in [0, 880)

    // len_abs = round(T * lengths[b]), ties-to-even to match jnp.round
    int len = __float2int_rn((float)TT * lengths[b]);

    float4 v;
    if (t >= len) {
        v = make_float4(0.f, 0.f, 0.f, 0.f);
    } else {
        const float* xb = x + (size_t)b * TT * CC;
        float vals[4];
#pragma unroll
        for (int j = 0; j < 4; ++j) {
            int k  = k0 + j;
            int c  = k / CTX;          // channel
            int i  = k - c * CTX;      // ctx offset, 0..10
            int tt = t + i - LEFTP;    // source time
            vals[j] = (tt >= 0 && tt < TT) ? xb[tt * CC + c] : 0.f;
        }
        v = make_float4(vals[0], vals[1], vals[2], vals[3]);
    }

    ((float4*)out)[gid] = v;
}

extern "C" void kernel_launch(void* const* d_in, const int* in_sizes, int n_in,
                              void* d_out, int out_size, void* d_ws, size_t ws_size,
                              hipStream_t stream) {
    const float* x       = (const float*)d_in[0];
    const float* lengths = (const float*)d_in[1];
    float* out           = (float*)d_out;

    const int block = 256;
    const int grid  = (TOTAL_Q + block - 1) / block;  // 55,000 blocks
    context_window_kernel<<<grid, block, 0, stream>>>(x, lengths, out);
}

// Round 2
// 233.325 us; speedup vs baseline: 1.0482x; 1.0482x over previous
//
#include <hip/hip_runtime.h>

// out[b, t, c*CTX + i] = (t < round(T*lengths[b]) && 0 <= t+i-LEFT < T)
//                          ? x[b, t+i-LEFT, c] : 0
// x: [32, 2000, 80] fp32; out: [32, 2000, 880] fp32 (225 MB, write-bound).
#define BB    32
#define TT    2000
#define CC    80
#define CTX   11
#define LEFTP 5

#define TL    40                 // time steps per block
#define NROWS (TL + 2 * LEFTP)   // 50 staged x-rows
#define S     84                 // LDS row stride in words: 336 B, 16B-aligned,
                                 // banks spread over {0,4,..,28} -> ~2-way (free)
#define ROWQ  220                // float4 per output time step (880/4)
#define NTILE (TT / TL)          // 50 tiles per batch

__global__ __launch_bounds__(256) void context_window_kernel(
    const float* __restrict__ x,
    const float* __restrict__ lengths,
    float* __restrict__ out)
{
    __shared__ float lds[NROWS * S];   // 16.8 KB

    const int tile = blockIdx.x % NTILE;
    const int b    = blockIdx.x / NTILE;
    const int t0   = tile * TL;
    const int tid  = threadIdx.x;

    // len_abs = round(T * lengths[b]), ties-to-even (matches jnp.round)
    const int len = __float2int_rn((float)TT * lengths[b]);

    float4* outq = (float4*)out + ((size_t)b * TT + t0) * ROWQ;

    // ---- fast path: entire tile masked -> coalesced zero fill ----
    if (t0 >= len) {
        const float4 z = make_float4(0.f, 0.f, 0.f, 0.f);
        for (int o = tid; o < TL * ROWQ; o += 256)
            outq[o] = z;
        return;
    }

    // ---- stage x rows [t0-5, t0+TL+5) into LDS (contiguous, coalesced) ----
    // 50 rows x 20 float4 = 1000 float4
    const float4* xb4 = (const float4*)(x + (size_t)b * TT * CC);
    for (int idx = tid; idx < NROWS * (CC / 4); idx += 256) {
        int r    = idx / (CC / 4);
        int c4   = idx - r * (CC / 4);
        int trow = t0 - LEFTP + r;
        float4 v = make_float4(0.f, 0.f, 0.f, 0.f);
        if (trow >= 0 && trow < TT) v = xb4[trow * (CC / 4) + c4];
        *(float4*)&lds[r * S + c4 * 4] = v;   // 16B-aligned (S*4 = 336)
    }
    __syncthreads();

    // ---- compute: thread owns one float4 column q, iterates over tl ----
    if (tid < ROWQ) {
        const int q = tid;
        // hoist the /11, %11 out of the hot loop (k = 4q+j fixed per thread)
        int caddr[4];
#pragma unroll
        for (int j = 0; j < 4; ++j) {
            int k = 4 * q + j;
            int c = k / CTX;
            int i = k - c * CTX;
            caddr[j] = i * S + c;   // add tl*S each iteration
        }
        float4* op = outq + q;
        for (int tl = 0; tl < TL; ++tl, op += ROWQ) {
            float4 v = make_float4(0.f, 0.f, 0.f, 0.f);
            if (t0 + tl < len) {
                const float* lp = &lds[tl * S];
                v.x = lp[caddr[0]];
                v.y = lp[caddr[1]];
                v.z = lp[caddr[2]];
                v.w = lp[caddr[3]];
            }
            *op = v;
        }
    }
}

extern "C" void kernel_launch(void* const* d_in, const int* in_sizes, int n_in,
                              void* d_out, int out_size, void* d_ws, size_t ws_size,
                              hipStream_t stream) {
    const float* x       = (const float*)d_in[0];
    const float* lengths = (const float*)d_in[1];
    float* out           = (float*)d_out;

    const int grid = BB * NTILE;   // 32 * 50 = 1600 blocks
    context_window_kernel<<<grid, 256, 0, stream>>>(x, lengths, out);
}